// Round 7
// baseline (30.442 us; speedup 1.0000x reference)
//
#include <hip/hip_runtime.h>
#include <math.h>

#define B_ 16
#define C_ 2048
#define Q_ 128
#define H_ 128
#define NEGV (-1000000000.0f)
#define REC_ 136  // record: [0]=m, [1]=z, [8..135]=partial q2c (unnormalized)

typedef short short8 __attribute__((ext_vector_type(8)));
typedef float f32x16 __attribute__((ext_vector_type(16)));
typedef float f32x4 __attribute__((ext_vector_type(4)));

__device__ __forceinline__ short f2bf(float f) {
  unsigned u = __builtin_bit_cast(unsigned, f);
  u += 0x7fffu + ((u >> 16) & 1u);
  return (short)(u >> 16);
}

// swizzled short-index of 16B chunk `ch` in row `row` of a [rows][128] bf16 tile
__device__ __forceinline__ int swz(int row, int ch) {
  return row * 128 + (((ch ^ (row & 7)) & 15) << 3);
}

__device__ __forceinline__ void nt_store4(float* p, float4 v) {
  __builtin_nontemporal_store(__builtin_bit_cast(f32x4, v), (f32x4*)p);
}
__device__ __forceinline__ void nt_store1(float* p, float v) {
  __builtin_nontemporal_store(v, p);
}

__device__ __forceinline__ float wave_max(float v) {
#pragma unroll
  for (int off = 32; off; off >>= 1) v = fmaxf(v, __shfl_xor(v, off, 64));
  return v;
}
__device__ __forceinline__ float wave_sum(float v) {
#pragma unroll
  for (int off = 32; off; off >>= 1) v += __shfl_xor(v, off, 64);
  return v;
}

// K0: q_bf16[row][h] = bf16(qry), sqm_g[row] = qmask ? qry_row.w_q : -1e12
// 2048 rows x 32 lanes; grid 256 x 256.
__global__ __launch_bounds__(256) void k0_pre(const float* __restrict__ qry,
                                              const float* __restrict__ W,
                                              const int* __restrict__ qmask,
                                              short* __restrict__ qb,
                                              float* __restrict__ sqm_g) {
  int t = blockIdx.x * 256 + threadIdx.x;
  int row = t >> 5, l = t & 31;
  float4 v = *(const float4*)&qry[(size_t)row * H_ + 4 * l];
  float4 wq = *(const float4*)&W[H_ + 4 * l];
  float s = v.x * wq.x + v.y * wq.y + v.z * wq.z + v.w * wq.w;
  short4 pk;
  pk.x = f2bf(v.x); pk.y = f2bf(v.y); pk.z = f2bf(v.z); pk.w = f2bf(v.w);
  *(short4*)&qb[(size_t)row * H_ + 4 * l] = pk;
  s += __shfl_xor(s, 1, 64);
  s += __shfl_xor(s, 2, 64);
  s += __shfl_xor(s, 4, 64);
  s += __shfl_xor(s, 8, 64);
  s += __shfl_xor(s, 16, 64);
  if (l == 0) sqm_g[row] = qmask[row] ? s : -1e12f;
}

// K1: per (b, 64-c tile): S^T via MFMA (A-frags from global q_bf16),
// softmax over q, c2q via MFMA, G chunks 1-3 (NT), fused q2c partial record.
// 512 thr = 8 waves, LDS ~52KB -> 2 blocks/CU.
__global__ __launch_bounds__(512, 4) void k1_main(
    const float* __restrict__ ctx, const short* __restrict__ qb,
    const float* __restrict__ W, const int* __restrict__ cmask,
    const float* __restrict__ sqm_g, float* __restrict__ out,
    float* __restrict__ pw) {
  __shared__ short QTs[16384];     // qry^T[h][q] bf16 swz (GEMM2 B)
  __shared__ short Xs[8192];       // x[c][h] bf16 swz; later a[c][q]
  __shared__ float scv[64];        // sc[c]
  __shared__ float sqm[128];       // masked sq[q]
  __shared__ float pm_lds[4][64];  // per-q-quarter max partials
  __shared__ float ps_lds[4][64];  // per-q-quarter sum partials
  __shared__ float mcv[64];        // masked per-c max (q2c path)
  __shared__ float wcv[64];        // exp(mcv - local m)
  __shared__ float mzl[2];         // local m, z
  __shared__ float pq2[2][128];    // q2c partial halves

  int b = blockIdx.x >> 5;
  int ct = blockIdx.x & 31;
  int tid = threadIdx.x;
  int bc0 = b * C_ + ct * 64;

  // ---- stage ctx tile (64 rows): out chunk1 (NT), sc[c], Xs ----
  {
    int c = tid >> 3, part = tid & 7;
    const float* crow = ctx + (size_t)(bc0 + c) * H_;
    float* orow = out + (size_t)(bc0 + c) * (4 * H_);
    float wsum = 0.f;
#pragma unroll
    for (int jj = 0; jj < 4; jj++) {
      int k = part + 8 * jj;  // float4 chunk 0..31
      float4 v = *(const float4*)&crow[4 * k];
      nt_store4(&orow[4 * k], v);  // G chunk 1 = ctx (exact fp32)
      float4 wc = *(const float4*)&W[4 * k];
      float4 wq = *(const float4*)&W[2 * H_ + 4 * k];
      wsum += v.x * wc.x + v.y * wc.y + v.z * wc.z + v.w * wc.w;
      short4 xp;
      xp.x = f2bf(v.x * wq.x);
      xp.y = f2bf(v.y * wq.y);
      xp.z = f2bf(v.z * wq.z);
      xp.w = f2bf(v.w * wq.w);
      *(short4*)&Xs[swz(c, k >> 1) + (k & 1) * 4] = xp;
    }
    wsum += __shfl_xor(wsum, 1, 64);
    wsum += __shfl_xor(wsum, 2, 64);
    wsum += __shfl_xor(wsum, 4, 64);
    if (part == 0) scv[c] = wsum;
  }
  // ---- build QTs = qry^T[h][q] from q_bf16 (no converts) ----
  {
    int qp = tid >> 3, p = tid & 7;  // qp 0..63 (q-row pairs)
    const short* r0 = qb + ((size_t)b * Q_ + 2 * qp) * H_;
    const short* r1 = r0 + H_;
#pragma unroll
    for (int pass = 0; pass < 2; pass++) {
      int h0 = p * 8 + pass * 64;
      short8 v0 = *(const short8*)&r0[h0];
      short8 v1 = *(const short8*)&r1[h0];
#pragma unroll
      for (int e = 0; e < 8; e++) {
        short2 pr;
        pr.x = v0[e];
        pr.y = v1[e];
        *(short2*)&QTs[swz(h0 + e, qp >> 2) + ((2 * qp) & 7)] = pr;
      }
    }
  }
  if (tid < 128) sqm[tid] = sqm_g[b * Q_ + tid];
  __syncthreads();  // s1

  int w = tid >> 6, lane = tid & 63;
  int lq = lane & 31, kg = lane >> 5;

  // ---- GEMM1: S^T = Q . X^T : M=q(128, 4 frags), N=c(64, 2 frags) ----
  int wm = w >> 1, wn = w & 1;
  f32x16 acc;
#pragma unroll
  for (int r = 0; r < 16; r++) acc[r] = 0.f;
  {
    const short* arow = qb + ((size_t)b * Q_ + wm * 32 + lq) * H_;
    int rB = wn * 32 + lq;
#pragma unroll
    for (int ks = 0; ks < 8; ks++) {
      int ch = 2 * ks + kg;
      short8 a = *(const short8*)&arow[ch * 8];
      short8 bb = *(const short8*)&Xs[swz(rB, ch)];
      acc = __builtin_amdgcn_mfma_f32_32x32x16_bf16(a, bb, acc, 0, 0, 0);
    }
  }

  // ---- softmax over q per c-column ----
  int cL = wn * 32 + lq;
  float scc = scv[cL];
  float pmax = -3e38f;
#pragma unroll
  for (int g = 0; g < 4; g++) {
    int q0 = wm * 32 + 8 * g + 4 * kg;
    float4 s4 = *(const float4*)&sqm[q0];
    float sv[4] = {s4.x, s4.y, s4.z, s4.w};
#pragma unroll
    for (int r = 0; r < 4; r++) {
      float Sv = acc[4 * g + r] + scc + sv[r];
      acc[4 * g + r] = Sv;
      pmax = fmaxf(pmax, Sv);
    }
  }
  pmax = fmaxf(pmax, __shfl_xor(pmax, 32, 64));
  if (lane < 32) pm_lds[wm][cL] = pmax;
  __syncthreads();  // s2: also guarantees all GEMM1 reads of Xs done

  float M = fmaxf(fmaxf(pm_lds[0][cL], pm_lds[1][cL]),
                  fmaxf(pm_lds[2][cL], pm_lds[3][cL]));
  if (wm == 0 && lane < 32) {
    mcv[cL] = cmask[bc0 + cL] ? M : NEGV;
  }
  float psum = 0.f;
#pragma unroll
  for (int g = 0; g < 4; g++) {
    int q0 = wm * 32 + 8 * g + 4 * kg;
    float e0 = __expf(acc[4 * g + 0] - M);
    float e1 = __expf(acc[4 * g + 1] - M);
    float e2 = __expf(acc[4 * g + 2] - M);
    float e3 = __expf(acc[4 * g + 3] - M);
    psum += e0 + e1 + e2 + e3;
    short4 pk;
    pk.x = f2bf(e0); pk.y = f2bf(e1); pk.z = f2bf(e2); pk.w = f2bf(e3);
    *(short4*)&Xs[swz(cL, q0 >> 3) + (q0 & 7)] = pk;  // a[c][q]
  }
  psum += __shfl_xor(psum, 32, 64);
  if (lane < 32) ps_lds[wm][cL] = psum;
  __syncthreads();  // s3: a[c][q] complete, mcv complete

  // ---- local q2c softmax weights over the 64 c-rows ----
  if (tid < 64) {
    float mv = mcv[tid];
    float lm = wave_max(mv);
    float ew = __expf(mv - lm);
    wcv[tid] = ew;
    float lz = wave_sum(ew);
    if (tid == 0) { mzl[0] = lm; mzl[1] = lz; }
  }

  // ---- GEMM2: c2q = a . qry : M=c(64, 2 frags), N=h(128, 4 frags) ----
  int wm2 = w & 1, wn2 = w >> 1;
  f32x16 o;
#pragma unroll
  for (int r = 0; r < 16; r++) o[r] = 0.f;
  {
    int rA = wm2 * 32 + lq, rB = wn2 * 32 + lq;
#pragma unroll
    for (int ks = 0; ks < 8; ks++) {
      int ch = 2 * ks + kg;
      short8 af = *(const short8*)&Xs[swz(rA, ch)];
      short8 bf_ = *(const short8*)&QTs[swz(rB, ch)];
      o = __builtin_amdgcn_mfma_f32_32x32x16_bf16(af, bf_, o, 0, 0, 0);
    }
  }
  __syncthreads();  // s4: wcv/mzl visible to all

  // ---- epilogue: chunks 2,3 (NT) + fused q2c partial ----
  int h = wn2 * 32 + lq;
  float part = 0.f;
#pragma unroll
  for (int g = 0; g < 4; g++) {
    int c0 = wm2 * 32 + 8 * g + 4 * kg;
    float4 z0 = *(const float4*)&ps_lds[0][c0];
    float4 z1 = *(const float4*)&ps_lds[1][c0];
    float4 z2 = *(const float4*)&ps_lds[2][c0];
    float4 z3 = *(const float4*)&ps_lds[3][c0];
    float zz[4] = {z0.x + z1.x + z2.x + z3.x, z0.y + z1.y + z2.y + z3.y,
                   z0.z + z1.z + z2.z + z3.z, z0.w + z1.w + z2.w + z3.w};
#pragma unroll
    for (int r = 0; r < 4; r++) {
      int c = c0 + r;
      float rz = 1.f / zz[r];
      size_t ro = (size_t)(bc0 + c) * (4 * H_);
      float ov = o[4 * g + r] * rz;
      float cv = ctx[(size_t)(bc0 + c) * H_ + h];
      nt_store1(&out[ro + H_ + h], ov);
      nt_store1(&out[ro + 2 * H_ + h], ov * cv);
      part += wcv[c] * cv;
    }
  }
  part += __shfl_xor(part, 32, 64);  // combine kg halves (same h)
  if (kg == 0) pq2[wm2][h] = part;
  __syncthreads();  // s5

  float* rec = pw + (size_t)blockIdx.x * REC_;
  if (tid < 128) rec[8 + tid] = pq2[0][tid] + pq2[1][tid];
  if (tid == 128) rec[0] = mzl[0];
  if (tid == 129) rec[1] = mzl[1];
}

// K4: per (b, 64-c tile): combine the 32 records of batch b (redundant,
// L2-hot) -> q2c in LDS, then write G chunk 4 = ctx * q2c. 256 threads.
__global__ __launch_bounds__(256) void k4_out(const float* __restrict__ ctx,
                                              const float* __restrict__ pw,
                                              float* __restrict__ out) {
  __shared__ float q2cs[128];
  int b = blockIdx.x >> 5;
  int ct = blockIdx.x & 31;
  int tid = threadIdx.x;
  int bc0 = b * C_ + ct * 64;

  if (tid < 128) {
    const float* base = pw + (size_t)b * 32 * REC_;
    float Mg = -3e38f;
#pragma unroll
    for (int t = 0; t < 32; t++) Mg = fmaxf(Mg, base[t * REC_]);
    float Zg = 0.f, s = 0.f;
#pragma unroll
    for (int t = 0; t < 32; t++) {
      float et = __expf(base[t * REC_] - Mg);
      Zg += et * base[t * REC_ + 1];
      s += et * base[t * REC_ + 8 + tid];
    }
    q2cs[tid] = s / Zg;
  }
  __syncthreads();

  int c = tid >> 2, part = tid & 3;  // 64 rows, 4 parts x 8 float4
  const float* crow = ctx + (size_t)(bc0 + c) * H_;
  float* orow = out + (size_t)(bc0 + c) * (4 * H_) + 3 * H_;
#pragma unroll
  for (int jj = 0; jj < 8; jj++) {
    int k = part + 4 * jj;
    float4 v = *(const float4*)&crow[4 * k];
    float4 g = *(const float4*)&q2cs[4 * k];
    nt_store4(&orow[4 * k],
              make_float4(v.x * g.x, v.y * g.y, v.z * g.z, v.w * g.w));
  }
}

extern "C" void kernel_launch(void* const* d_in, const int* in_sizes, int n_in,
                              void* d_out, int out_size, void* d_ws,
                              size_t ws_size, hipStream_t stream) {
  const float* ctx = (const float*)d_in[0];
  const float* qry = (const float*)d_in[1];
  const float* W = (const float*)d_in[2];
  const int* cmask = (const int*)d_in[3];
  const int* qmask = (const int*)d_in[4];
  float* out = (float*)d_out;

  // ws layout: q_bf16 (512KB) | sqm_g (8KB) | pw (512 recs * 136 floats)
  short* qb = (short*)d_ws;
  float* sqm_g = (float*)((char*)d_ws + (size_t)B_ * Q_ * H_ * sizeof(short));
  float* pw = sqm_g + B_ * Q_;

  k0_pre<<<256, 256, 0, stream>>>(qry, W, qmask, qb, sqm_g);
  k1_main<<<B_ * 32, 512, 0, stream>>>(ctx, qb, W, cmask, sqm_g, out, pw);
  k4_out<<<B_ * 32, 256, 0, stream>>>(ctx, pw, out);
}